// Round 14
// baseline (100.486 us; speedup 1.0000x reference)
//
#include <hip/hip_runtime.h>
#include <stdint.h>

#define NN 50000
#define NE 800000
#define INC 128
#define HID 64
#define LDP 72     // padded LDS row stride (bf16 elems); 144B rows (16B-aligned)

#define NBUK 391   // ceil(NN/128) buckets; bucket = dst >> 7
#define CAP 2368   // edges/bucket capacity: mean 2048 + ~7 sigma
#define TILE 2048  // edges per binA block (small tile -> high occupancy)
#define NTA 391    // ceil(NE/TILE)
#define XBLK 782   // ceil(NN/64) xform/layer blocks
#define NGRP 6250  // NN/8 perm groups

typedef __attribute__((ext_vector_type(8))) short short8;
typedef __attribute__((ext_vector_type(4))) float f32x4;

__device__ __forceinline__ unsigned short f2b(float f) {
    unsigned int u = __builtin_bit_cast(unsigned int, f);
    u += 0x7FFFu + ((u >> 16) & 1u);   // RNE (finite inputs)
    return (unsigned short)(u >> 16);
}
__device__ __forceinline__ float b2f_lo(unsigned int v) {
    return __builtin_bit_cast(float, v << 16);
}
__device__ __forceinline__ float b2f_hi(unsigned int v) {
    return __builtin_bit_cast(float, v & 0xFFFF0000u);
}
__device__ __forceinline__ unsigned int pk2(float lo, float hi) {
    return (unsigned int)f2b(fmaxf(lo, 0.f)) |
           ((unsigned int)f2b(fmaxf(hi, 0.f)) << 16);
}

// ---------------------------------------------------------------------------
// Edge-dtype detection: int64 LE with values <50000 => odd 32-bit words all 0.
__device__ __forceinline__ bool is_i32(const int* __restrict__ e32) {
    return (e32[1] | e32[3] | e32[5] | e32[7]) != 0;
}
__device__ __forceinline__ int load_src(const int* e32, bool i32, int e) {
    return i32 ? e32[e] : e32[2 * e];
}
__device__ __forceinline__ int load_dst(const int* e32, bool i32, int e) {
    return i32 ? e32[NE + e] : e32[2 * (NE + e)];
}

// ---------------------------------------------------------------------------
// wconv: weight transpose+bf16 (blocks 0..79) AND gcur zeroing (block 80).
__global__ __launch_bounds__(256) void wconv(const float* __restrict__ w1a,
                                             const float* __restrict__ w1b,
                                             const float* __restrict__ w2a,
                                             const float* __restrict__ w2b,
                                             unsigned short* __restrict__ w1aT,
                                             unsigned short* __restrict__ w1bT,
                                             unsigned short* __restrict__ w2aT,
                                             unsigned short* __restrict__ w2bT,
                                             int* __restrict__ gcur) {
    if (blockIdx.x == 80) {
        gcur[2 * threadIdx.x] = 0;
        gcur[2 * threadIdx.x + 1] = 0;
        return;
    }
    int i = blockIdx.x * 256 + threadIdx.x;
    if (i < 8192) {
        int n = i >> 7, k = i & 127;
        w1aT[n * 128 + k] = f2b(w1a[k * 64 + n]);
    } else if (i < 12288) {
        int j = i - 8192, n = j >> 6, k = j & 63;
        w1bT[n * 64 + k] = f2b(w1b[k * 64 + n]);
    } else if (i < 16384) {
        int j = i - 12288, n = j >> 6, k = j & 63;
        w2aT[n * 64 + k] = f2b(w2a[k * 64 + n]);
    } else if (i < 20480) {
        int j = i - 16384, n = j >> 6, k = j & 63;
        w2bT[n * 64 + k] = f2b(w2b[k * 64 + n]);
    }
}

// ---------------------------------------------------------------------------
// binA: histogram-sort 2048-edge tiles into 391 dst-buckets; coalesced output.
__global__ __launch_bounds__(256) void binA(const int* __restrict__ e32,
                                            int* __restrict__ gcur,
                                            unsigned int* __restrict__ binned) {
    __shared__ unsigned int stage[TILE];
    __shared__ unsigned int sorted[TILE];
    __shared__ int cnt[512];
    __shared__ int off0[512];
    __shared__ int base[512];
    const int t = threadIdx.x;
    const bool i32m = is_i32(e32);
    cnt[t] = 0; cnt[t + 256] = 0;
    __syncthreads();

    const int tb = blockIdx.x * TILE;
    int nval = NE - tb; if (nval > TILE) nval = TILE;

    for (int k = 0; k < TILE; k += 256) {
        int j = k + t;
        if (j < nval) {
            int e = tb + j;
            int src = load_src(e32, i32m, e);
            int dst = load_dst(e32, i32m, e);
            stage[j] = ((unsigned)dst << 16) | (unsigned)src;
            atomicAdd(&cnt[dst >> 7], 1);
        }
    }
    __syncthreads();

    for (int off = 1; off < 512; off <<= 1) {
        int a = (t >= off) ? cnt[t - off] : 0;
        int b2 = (t + 256 >= off) ? cnt[t + 256 - off] : 0;
        __syncthreads();
        cnt[t] += a; cnt[t + 256] += b2;
        __syncthreads();
    }
    int inc0 = cnt[t], inc1 = cnt[t + 256];
    int ex0 = (t == 0) ? 0 : cnt[t - 1];
    int ex1 = cnt[t + 255];
    __syncthreads();
    off0[t] = ex0; off0[t + 256] = ex1;
    cnt[t] = ex0; cnt[t + 256] = ex1;   // cnt becomes allocation cursor
    __syncthreads();

    for (int k = 0; k < TILE; k += 256) {
        int j = k + t;
        if (j < nval) {
            unsigned w = stage[j];
            int b = (int)(w >> 16) >> 7;
            int r = atomicAdd(&cnt[b], 1);
            sorted[r] = w;
        }
    }
    __syncthreads();

    if (t < NBUK && (inc0 - ex0) > 0) base[t] = atomicAdd(&gcur[t], inc0 - ex0);
    if (t + 256 < NBUK && (inc1 - ex1) > 0)
        base[t + 256] = atomicAdd(&gcur[t + 256], inc1 - ex1);
    __syncthreads();

    for (int k = 0; k < TILE; k += 256) {
        int j = k + t;
        if (j < nval) {
            unsigned w = sorted[j];
            int b = (int)(w >> 16) >> 7;
            int pos = base[b] + (j - off0[b]);
            if (pos < CAP) binned[(size_t)b * CAP + pos] = w;
        }
    }
}

// ---------------------------------------------------------------------------
// binbx: blocks [0,NBUK) run binB (bucket CSR + degree-sorted perm);
// blocks [NBUK, NBUK+XBLK) run xform (xw = x @ w1a via MFMA). Independent.
__global__ __launch_bounds__(256) void binbx(const int* __restrict__ gcur,
                                             const unsigned int* __restrict__ binned,
                                             int* __restrict__ row_start,
                                             int* __restrict__ deg,
                                             unsigned short* __restrict__ col16,
                                             int* __restrict__ perm,
                                             const float* __restrict__ x,
                                             const unsigned short* __restrict__ w1aT,
                                             unsigned short* __restrict__ xw) {
    __shared__ unsigned int stg[CAP];
    __shared__ unsigned short srt[CAP];
    __shared__ int cnt[128], cur[128];
    __shared__ int hcnt[64];

    if (blockIdx.x >= NBUK) {
        // ---- xform part ----
        const int w = threadIdx.x >> 6, lane = threadIdx.x & 63;
        const int r = lane & 15, hk = lane >> 4;
        const int base = (blockIdx.x - NBUK) * 64 + w * 16;
        f32x4 acc[4] = {};
#pragma unroll
        for (int s = 0; s < 4; ++s) {  // K = 128 = 4 x 32
            int row = base + r; if (row >= NN) row = NN - 1;
            const float* xp = x + (size_t)row * INC + 32 * s + 8 * hk;
            float4 u0 = *(const float4*)xp;
            float4 u1 = *(const float4*)(xp + 4);
            short8 a;
            a[0] = (short)f2b(u0.x); a[1] = (short)f2b(u0.y);
            a[2] = (short)f2b(u0.z); a[3] = (short)f2b(u0.w);
            a[4] = (short)f2b(u1.x); a[5] = (short)f2b(u1.y);
            a[6] = (short)f2b(u1.z); a[7] = (short)f2b(u1.w);
#pragma unroll
            for (int ct = 0; ct < 4; ++ct) {
                short8 b = *(const short8*)(w1aT + (16 * ct + r) * 128 + 32 * s + 8 * hk);
                acc[ct] = __builtin_amdgcn_mfma_f32_16x16x32_bf16(a, b, acc[ct], 0, 0, 0);
            }
        }
#pragma unroll
        for (int ct = 0; ct < 4; ++ct)
#pragma unroll
            for (int reg = 0; reg < 4; ++reg) {
                int node = base + 4 * hk + reg;
                if (node < NN) xw[(size_t)node * HID + 16 * ct + r] = f2b(acc[ct][reg]);
            }
        return;
    }

    // ---- binB part ----
    const int b = blockIdx.x, t = threadIdx.x;
    const int nb0 = b * 128;
    int nb = NN - nb0; if (nb > 128) nb = 128;
    int ec = gcur[b]; if (ec > CAP) ec = CAP;

    if (t < 128) cnt[t] = 0;
    if (t < 64) hcnt[t] = 0;
    __syncthreads();
    for (int j = t; j < ec; j += 256) {
        unsigned w = binned[(size_t)b * CAP + j];
        stg[j] = w;
        atomicAdd(&cnt[(w >> 16) & 127], 1);
    }
    __syncthreads();
    for (int off = 1; off < 128; off <<= 1) {
        int a = 0;
        if (t < 128 && t >= off) a = cnt[t - off];
        __syncthreads();
        if (t < 128) cnt[t] += a;
        __syncthreads();
    }
    int ex = 0, mydeg = 0;
    if (t < 128) ex = (t == 0) ? 0 : cnt[t - 1];
    __syncthreads();
    if (t < nb) {
        mydeg = cnt[t] - ex;
        deg[nb0 + t] = mydeg;
        row_start[nb0 + t] = b * CAP + ex;
        cur[t] = ex;
        int dc = mydeg < 64 ? mydeg : 63;
        atomicAdd(&hcnt[dc], 1);
    }
    __syncthreads();
    for (int j = t; j < ec; j += 256) {
        unsigned w = stg[j];
        int r = atomicAdd(&cur[(w >> 16) & 127], 1);
        srt[r] = (unsigned short)(w & 0xFFFFu);
    }
    for (int off = 1; off < 64; off <<= 1) {
        int a = 0;
        if (t < 64 && t >= off) a = hcnt[t - off];
        __syncthreads();
        if (t < 64) hcnt[t] += a;
        __syncthreads();
    }
    int hex = 0;
    if (t < 64) hex = (t == 0) ? 0 : hcnt[t - 1];
    __syncthreads();
    if (t < 64) hcnt[t] = hex;   // hcnt becomes cursor
    __syncthreads();
    if (t < nb) {
        int dc = mydeg < 64 ? mydeg : 63;
        int rank = atomicAdd(&hcnt[dc], 1);
        perm[nb0 + rank] = nb0 + t;
    }
    __syncthreads();
    for (int j = t; j < ec; j += 256)
        col16[(size_t)b * CAP + j] = srt[j];
}

// ---------------------------------------------------------------------------
// Gather phase (device fn): 8 waves x 8 nodes -> 64-row LDS t-tile (bf16).
// Group striping: wave wv of block blk handles perm-group gid = wv*XBLK+blk,
// so every block averages the degree distribution (no slow-tail blocks) while
// each wave keeps degree-uniform groups. nodetab[lslot] carries the node id
// (or -1) to the MFMA phase.
__device__ __forceinline__ void gather_to_lds(const unsigned short* __restrict__ feat,
                                              const int* __restrict__ row_start,
                                              const int* __restrict__ deg,
                                              const unsigned short* __restrict__ col16,
                                              const int* __restrict__ perm,
                                              const float* __restrict__ bias,
                                              unsigned short* __restrict__ t_lds,
                                              int* __restrict__ nodetab,
                                              int wv, int lane, int blk) {
    const int g = lane >> 3, cl = lane & 7;
    const int lslot = wv * 8 + g;
    const int gid = wv * XBLK + blk;
    const bool active = gid < NGRP;
    const int node = active ? perm[gid * 8 + g] : -1;
    if (cl == 0) nodetab[lslot] = node;

    const unsigned int* f32p = (const unsigned int*)feat;
    int d = active ? deg[node] : 0;
    const int rs = active ? row_start[node] : 0;
    int dmax = d;
    dmax = max(dmax, __shfl_xor(dmax, 8, 64));
    dmax = max(dmax, __shfl_xor(dmax, 16, 64));
    dmax = max(dmax, __shfl_xor(dmax, 32, 64));

    float a0 = 0.f, a1 = 0.f, a2 = 0.f, a3 = 0.f;
    float a4 = 0.f, a5 = 0.f, a6 = 0.f, a7 = 0.f;
    if (active) {
        const float4* b4 = (const float4*)bias;
        float4 bb0 = b4[cl * 2], bb1 = b4[cl * 2 + 1];
        uint4 sv = *(const uint4*)(f32p + (size_t)node * 32 + cl * 4);
        a0 = b2f_lo(sv.x) + bb0.x; a1 = b2f_hi(sv.x) + bb0.y;
        a2 = b2f_lo(sv.y) + bb0.z; a3 = b2f_hi(sv.y) + bb0.w;
        a4 = b2f_lo(sv.z) + bb1.x; a5 = b2f_hi(sv.z) + bb1.y;
        a6 = b2f_lo(sv.w) + bb1.z; a7 = b2f_hi(sv.w) + bb1.w;
    }
    for (int rb = 0; rb < dmax; rb += 8) {
        int stage = (rb + cl < d) ? (int)col16[(size_t)rs + rb + cl] : 0;
#pragma unroll
        for (int e = 0; e < 8; ++e) {
            int s = __shfl(stage, g * 8 + e, 64);
            if (rb + e < d) {
                uint4 v = *(const uint4*)(f32p + (size_t)s * 32 + cl * 4);
                a0 += b2f_lo(v.x); a1 += b2f_hi(v.x);
                a2 += b2f_lo(v.y); a3 += b2f_hi(v.y);
                a4 += b2f_lo(v.z); a5 += b2f_hi(v.z);
                a6 += b2f_lo(v.w); a7 += b2f_hi(v.w);
            }
        }
    }
    uint4 o;
    o.x = pk2(a0, a1); o.y = pk2(a2, a3);
    o.z = pk2(a4, a5); o.w = pk2(a6, a7);
    *(uint4*)(t_lds + (size_t)lslot * LDP + cl * 8) = o;
}

// ---------------------------------------------------------------------------
// layer1: gather(xw,+b1a,relu)->LDS | barrier | waves 0-3:
//   h = relu(t@w1bT+b1b) -> LDS ; p[node] = h@w2aT (bf16)
__global__ __launch_bounds__(512) void layer1(const unsigned short* __restrict__ xw,
                                              const int* __restrict__ row_start,
                                              const int* __restrict__ deg,
                                              const unsigned short* __restrict__ col16,
                                              const int* __restrict__ perm,
                                              const float* __restrict__ b1a,
                                              const unsigned short* __restrict__ w1bT,
                                              const float* __restrict__ b1b,
                                              const unsigned short* __restrict__ w2aT,
                                              unsigned short* __restrict__ p) {
    __shared__ __align__(16) unsigned short t_lds[64 * LDP];
    __shared__ __align__(16) unsigned short h_lds[4][16 * LDP];
    __shared__ int nodetab[64];
    const int wv = threadIdx.x >> 6, lane = threadIdx.x & 63;

    gather_to_lds(xw, row_start, deg, col16, perm, b1a, t_lds, nodetab,
                  wv, lane, blockIdx.x);
    __syncthreads();
    if (wv >= 4) return;

    const int r = lane & 15, hk = lane >> 4;
    const unsigned short* tw = t_lds + wv * 16 * LDP;
    unsigned short* hw = h_lds[wv];

    f32x4 acc[4];
#pragma unroll
    for (int ct = 0; ct < 4; ++ct) {
        float bbv = b1b[16 * ct + r];
        acc[ct][0] = bbv; acc[ct][1] = bbv; acc[ct][2] = bbv; acc[ct][3] = bbv;
    }
#pragma unroll
    for (int s = 0; s < 2; ++s) {
        short8 a = *(const short8*)(tw + r * LDP + 32 * s + 8 * hk);
#pragma unroll
        for (int ct = 0; ct < 4; ++ct) {
            short8 b = *(const short8*)(w1bT + (16 * ct + r) * 64 + 32 * s + 8 * hk);
            acc[ct] = __builtin_amdgcn_mfma_f32_16x16x32_bf16(a, b, acc[ct], 0, 0, 0);
        }
    }
#pragma unroll
    for (int ct = 0; ct < 4; ++ct)
#pragma unroll
        for (int reg = 0; reg < 4; ++reg)
            hw[(4 * hk + reg) * LDP + 16 * ct + r] = f2b(fmaxf(acc[ct][reg], 0.f));

    f32x4 acc2[4] = {};
#pragma unroll
    for (int s = 0; s < 2; ++s) {
        short8 a = *(const short8*)(hw + r * LDP + 32 * s + 8 * hk);
#pragma unroll
        for (int ct = 0; ct < 4; ++ct) {
            short8 b = *(const short8*)(w2aT + (16 * ct + r) * 64 + 32 * s + 8 * hk);
            acc2[ct] = __builtin_amdgcn_mfma_f32_16x16x32_bf16(a, b, acc2[ct], 0, 0, 0);
        }
    }
#pragma unroll
    for (int reg = 0; reg < 4; ++reg) {
        int node = nodetab[wv * 16 + 4 * hk + reg];
        if (node >= 0) {
#pragma unroll
            for (int ct = 0; ct < 4; ++ct)
                p[(size_t)node * HID + 16 * ct + r] = f2b(acc2[ct][reg]);
        }
    }
}

// ---------------------------------------------------------------------------
// layer2: gather(p,+b2a,relu)->LDS | barrier | waves 0-3:
//   z = t@w2bT + b2b ; in-register log_softmax ; out[node] f32
__global__ __launch_bounds__(512) void layer2(const unsigned short* __restrict__ pin,
                                              const int* __restrict__ row_start,
                                              const int* __restrict__ deg,
                                              const unsigned short* __restrict__ col16,
                                              const int* __restrict__ perm,
                                              const float* __restrict__ b2a,
                                              const unsigned short* __restrict__ w2bT,
                                              const float* __restrict__ b2b,
                                              float* __restrict__ out) {
    __shared__ __align__(16) unsigned short t_lds[64 * LDP];
    __shared__ int nodetab[64];
    const int wv = threadIdx.x >> 6, lane = threadIdx.x & 63;

    gather_to_lds(pin, row_start, deg, col16, perm, b2a, t_lds, nodetab,
                  wv, lane, blockIdx.x);
    __syncthreads();
    if (wv >= 4) return;

    const int r = lane & 15, hk = lane >> 4;
    const unsigned short* tw = t_lds + wv * 16 * LDP;

    f32x4 acc[4];
#pragma unroll
    for (int ct = 0; ct < 4; ++ct) {
        float bbv = b2b[16 * ct + r];
        acc[ct][0] = bbv; acc[ct][1] = bbv; acc[ct][2] = bbv; acc[ct][3] = bbv;
    }
#pragma unroll
    for (int s = 0; s < 2; ++s) {
        short8 a = *(const short8*)(tw + r * LDP + 32 * s + 8 * hk);
#pragma unroll
        for (int ct = 0; ct < 4; ++ct) {
            short8 b = *(const short8*)(w2bT + (16 * ct + r) * 64 + 32 * s + 8 * hk);
            acc[ct] = __builtin_amdgcn_mfma_f32_16x16x32_bf16(a, b, acc[ct], 0, 0, 0);
        }
    }
#pragma unroll
    for (int reg = 0; reg < 4; ++reg) {
        float m = fmaxf(fmaxf(acc[0][reg], acc[1][reg]),
                        fmaxf(acc[2][reg], acc[3][reg]));
        for (int off = 1; off < 16; off <<= 1)
            m = fmaxf(m, __shfl_xor(m, off, 64));
        float s = expf(acc[0][reg] - m) + expf(acc[1][reg] - m) +
                  expf(acc[2][reg] - m) + expf(acc[3][reg] - m);
        for (int off = 1; off < 16; off <<= 1)
            s += __shfl_xor(s, off, 64);
        float ls = m + logf(s);
        int node = nodetab[wv * 16 + 4 * hk + reg];
        if (node >= 0) {
            float* op = out + (size_t)node * HID;
            op[r]      = acc[0][reg] - ls;
            op[16 + r] = acc[1][reg] - ls;
            op[32 + r] = acc[2][reg] - ls;
            op[48 + r] = acc[3][reg] - ls;
        }
    }
}

// ---------------------------------------------------------------------------
extern "C" void kernel_launch(void* const* d_in, const int* in_sizes, int n_in,
                              void* d_out, int out_size, void* d_ws, size_t ws_size,
                              hipStream_t stream) {
    const float* x   = (const float*)d_in[0];
    const int*   e32 = (const int*)d_in[1];
    const float* w1a = (const float*)d_in[2];
    const float* b1a = (const float*)d_in[3];
    const float* w1b = (const float*)d_in[4];
    const float* b1b = (const float*)d_in[5];
    const float* w2a = (const float*)d_in[6];
    const float* b2a = (const float*)d_in[7];
    const float* w2b = (const float*)d_in[8];
    const float* b2b = (const float*)d_in[9];
    float* out = (float*)d_out;

    // ws layout (32-bit words):
    // [gcur 512][col16 NBUK*CAP u16][row_start NN][deg NN][perm NN]
    // [xw NN*64 u16][p NN*64 u16 (binned u32 aliases it)]
    // [w1aT][w1bT][w2aT][w2bT]
    int* W = (int*)d_ws;
    int* gcur = W;                                            // 512 words
    unsigned short* col16 = (unsigned short*)(W + 512);       // NBUK*CAP u16
    int* row_start = W + 512 + (NBUK * CAP) / 2;              // even product
    int* deg       = row_start + NN;
    int* perm      = deg + NN;
    unsigned short* xw = (unsigned short*)(perm + NN);
    unsigned short* p  = xw + (size_t)NN * HID;
    unsigned int* binned = (unsigned int*)p;   // p unwritten until layer1
    unsigned short* w1aT = p + (size_t)NN * HID;
    unsigned short* w1bT = w1aT + 64 * 128;
    unsigned short* w2aT = w1bT + 64 * 64;
    unsigned short* w2bT = w2aT + 64 * 64;

    // 1. weights + gcur zero
    wconv<<<81, 256, 0, stream>>>(w1a, w1b, w2a, w2b, w1aT, w1bT, w2aT, w2bT, gcur);

    // 2. bucket histogram sort
    binA<<<NTA, 256, 0, stream>>>(e32, gcur, binned);

    // 3. per-bucket CSR + degree perm, co-dispatched with xw = x @ w1a
    binbx<<<NBUK + XBLK, 256, 0, stream>>>(gcur, binned, row_start, deg, col16,
                                           perm, x, w1aT, xw);

    // 4. layer 1 fused: gather+relu -> MLP(w1b,relu,w2a) -> p
    layer1<<<XBLK, 512, 0, stream>>>(xw, row_start, deg, col16, perm,
                                     b1a, w1bT, b1b, w2aT, p);

    // 5. layer 2 fused: gather+relu -> w2b + log_softmax -> out
    layer2<<<XBLK, 512, 0, stream>>>(p, row_start, deg, col16, perm,
                                     b2a, w2bT, b2b, out);
}

// Round 15
// 98.803 us; speedup vs baseline: 1.0170x; 1.0170x over previous
//
#include <hip/hip_runtime.h>
#include <stdint.h>

#define NN 50000
#define NE 800000
#define INC 128
#define HID 64
#define LDP 72     // padded LDS row stride (bf16 elems); 144B rows (16B-aligned)

#define NBUK 391   // ceil(NN/128) buckets; bucket = dst >> 7
#define CAP 2368   // edges/bucket capacity: mean 2048 + ~7 sigma
#define TILE 2048  // edges per binA block (small tile -> high occupancy)
#define NTA 391    // ceil(NE/TILE)
#define XBLK 782   // ceil(NN/64) xform/layer blocks
#define NGRP 6250  // NN/8 perm groups

typedef __attribute__((ext_vector_type(8))) short short8;
typedef __attribute__((ext_vector_type(4))) float f32x4;

__device__ __forceinline__ unsigned short f2b(float f) {
    unsigned int u = __builtin_bit_cast(unsigned int, f);
    u += 0x7FFFu + ((u >> 16) & 1u);   // RNE (finite inputs)
    return (unsigned short)(u >> 16);
}
__device__ __forceinline__ float b2f_lo(unsigned int v) {
    return __builtin_bit_cast(float, v << 16);
}
__device__ __forceinline__ float b2f_hi(unsigned int v) {
    return __builtin_bit_cast(float, v & 0xFFFF0000u);
}
__device__ __forceinline__ unsigned int pk2(float lo, float hi) {
    return (unsigned int)f2b(fmaxf(lo, 0.f)) |
           ((unsigned int)f2b(fmaxf(hi, 0.f)) << 16);
}

// ---------------------------------------------------------------------------
// Edge-dtype detection: int64 LE with values <50000 => odd 32-bit words all 0.
__device__ __forceinline__ bool is_i32(const int* __restrict__ e32) {
    return (e32[1] | e32[3] | e32[5] | e32[7]) != 0;
}
__device__ __forceinline__ int load_src(const int* e32, bool i32, int e) {
    return i32 ? e32[e] : e32[2 * e];
}
__device__ __forceinline__ int load_dst(const int* e32, bool i32, int e) {
    return i32 ? e32[NE + e] : e32[2 * (NE + e)];
}

// ---------------------------------------------------------------------------
// wconv: weight transpose+bf16 (blocks 0..79) AND gcur zeroing (block 80).
__global__ __launch_bounds__(256) void wconv(const float* __restrict__ w1a,
                                             const float* __restrict__ w1b,
                                             const float* __restrict__ w2a,
                                             const float* __restrict__ w2b,
                                             unsigned short* __restrict__ w1aT,
                                             unsigned short* __restrict__ w1bT,
                                             unsigned short* __restrict__ w2aT,
                                             unsigned short* __restrict__ w2bT,
                                             int* __restrict__ gcur) {
    if (blockIdx.x == 80) {
        gcur[2 * threadIdx.x] = 0;
        gcur[2 * threadIdx.x + 1] = 0;
        return;
    }
    int i = blockIdx.x * 256 + threadIdx.x;
    if (i < 8192) {
        int n = i >> 7, k = i & 127;
        w1aT[n * 128 + k] = f2b(w1a[k * 64 + n]);
    } else if (i < 12288) {
        int j = i - 8192, n = j >> 6, k = j & 63;
        w1bT[n * 64 + k] = f2b(w1b[k * 64 + n]);
    } else if (i < 16384) {
        int j = i - 12288, n = j >> 6, k = j & 63;
        w2aT[n * 64 + k] = f2b(w2a[k * 64 + n]);
    } else if (i < 20480) {
        int j = i - 16384, n = j >> 6, k = j & 63;
        w2bT[n * 64 + k] = f2b(w2b[k * 64 + n]);
    }
}

// ---------------------------------------------------------------------------
// binax: blocks [0,NTA) histogram-sort 2048-edge tiles into dst-buckets;
// blocks [NTA, NTA+XBLK) run xform (xw = x @ w1a via MFMA). Both depend only
// on earlier dispatches (e32/gcur=0 resp. w1aT), so they pack one grid.
__global__ __launch_bounds__(256) void binax(const int* __restrict__ e32,
                                             int* __restrict__ gcur,
                                             unsigned int* __restrict__ binned,
                                             const float* __restrict__ x,
                                             const unsigned short* __restrict__ w1aT,
                                             unsigned short* __restrict__ xw) {
    __shared__ unsigned int stage[TILE];
    __shared__ unsigned int sorted[TILE];
    __shared__ int cnt[512];
    __shared__ int off0[512];
    __shared__ int base[512];

    if (blockIdx.x >= NTA) {
        // ---- xform part ----
        const int w = threadIdx.x >> 6, lane = threadIdx.x & 63;
        const int r = lane & 15, hk = lane >> 4;
        const int nb = (blockIdx.x - NTA) * 64 + w * 16;
        f32x4 acc[4] = {};
#pragma unroll
        for (int s = 0; s < 4; ++s) {  // K = 128 = 4 x 32
            int row = nb + r; if (row >= NN) row = NN - 1;
            const float* xp = x + (size_t)row * INC + 32 * s + 8 * hk;
            float4 u0 = *(const float4*)xp;
            float4 u1 = *(const float4*)(xp + 4);
            short8 a;
            a[0] = (short)f2b(u0.x); a[1] = (short)f2b(u0.y);
            a[2] = (short)f2b(u0.z); a[3] = (short)f2b(u0.w);
            a[4] = (short)f2b(u1.x); a[5] = (short)f2b(u1.y);
            a[6] = (short)f2b(u1.z); a[7] = (short)f2b(u1.w);
#pragma unroll
            for (int ct = 0; ct < 4; ++ct) {
                short8 b = *(const short8*)(w1aT + (16 * ct + r) * 128 + 32 * s + 8 * hk);
                acc[ct] = __builtin_amdgcn_mfma_f32_16x16x32_bf16(a, b, acc[ct], 0, 0, 0);
            }
        }
#pragma unroll
        for (int ct = 0; ct < 4; ++ct)
#pragma unroll
            for (int reg = 0; reg < 4; ++reg) {
                int node = nb + 4 * hk + reg;
                if (node < NN) xw[(size_t)node * HID + 16 * ct + r] = f2b(acc[ct][reg]);
            }
        return;
    }

    // ---- binA part ----
    const int t = threadIdx.x;
    const bool i32m = is_i32(e32);
    cnt[t] = 0; cnt[t + 256] = 0;
    __syncthreads();

    const int tb = blockIdx.x * TILE;
    int nval = NE - tb; if (nval > TILE) nval = TILE;

    for (int k = 0; k < TILE; k += 256) {
        int j = k + t;
        if (j < nval) {
            int e = tb + j;
            int src = load_src(e32, i32m, e);
            int dst = load_dst(e32, i32m, e);
            stage[j] = ((unsigned)dst << 16) | (unsigned)src;
            atomicAdd(&cnt[dst >> 7], 1);
        }
    }
    __syncthreads();

    for (int off = 1; off < 512; off <<= 1) {
        int a = (t >= off) ? cnt[t - off] : 0;
        int b2 = (t + 256 >= off) ? cnt[t + 256 - off] : 0;
        __syncthreads();
        cnt[t] += a; cnt[t + 256] += b2;
        __syncthreads();
    }
    int inc0 = cnt[t], inc1 = cnt[t + 256];
    int ex0 = (t == 0) ? 0 : cnt[t - 1];
    int ex1 = cnt[t + 255];
    __syncthreads();
    off0[t] = ex0; off0[t + 256] = ex1;
    cnt[t] = ex0; cnt[t + 256] = ex1;   // cnt becomes allocation cursor
    __syncthreads();

    for (int k = 0; k < TILE; k += 256) {
        int j = k + t;
        if (j < nval) {
            unsigned w = stage[j];
            int b = (int)(w >> 16) >> 7;
            int r = atomicAdd(&cnt[b], 1);
            sorted[r] = w;
        }
    }
    __syncthreads();

    if (t < NBUK && (inc0 - ex0) > 0) base[t] = atomicAdd(&gcur[t], inc0 - ex0);
    if (t + 256 < NBUK && (inc1 - ex1) > 0)
        base[t + 256] = atomicAdd(&gcur[t + 256], inc1 - ex1);
    __syncthreads();

    for (int k = 0; k < TILE; k += 256) {
        int j = k + t;
        if (j < nval) {
            unsigned w = sorted[j];
            int b = (int)(w >> 16) >> 7;
            int pos = base[b] + (j - off0[b]);
            if (pos < CAP) binned[(size_t)b * CAP + pos] = w;
        }
    }
}

// ---------------------------------------------------------------------------
// binb: per bucket (128 nodes): sort staged edges by node -> CSR (coalesced),
// plus per-bucket counting sort of node ids by degree -> perm.
__global__ __launch_bounds__(256) void binb(const int* __restrict__ gcur,
                                            const unsigned int* __restrict__ binned,
                                            int* __restrict__ row_start,
                                            int* __restrict__ deg,
                                            unsigned short* __restrict__ col16,
                                            int* __restrict__ perm) {
    __shared__ unsigned int stg[CAP];
    __shared__ unsigned short srt[CAP];
    __shared__ int cnt[128], cur[128];
    __shared__ int hcnt[64];

    const int b = blockIdx.x, t = threadIdx.x;
    const int nb0 = b * 128;
    int nb = NN - nb0; if (nb > 128) nb = 128;
    int ec = gcur[b]; if (ec > CAP) ec = CAP;

    if (t < 128) cnt[t] = 0;
    if (t < 64) hcnt[t] = 0;
    __syncthreads();
    for (int j = t; j < ec; j += 256) {
        unsigned w = binned[(size_t)b * CAP + j];
        stg[j] = w;
        atomicAdd(&cnt[(w >> 16) & 127], 1);
    }
    __syncthreads();
    for (int off = 1; off < 128; off <<= 1) {
        int a = 0;
        if (t < 128 && t >= off) a = cnt[t - off];
        __syncthreads();
        if (t < 128) cnt[t] += a;
        __syncthreads();
    }
    int ex = 0, mydeg = 0;
    if (t < 128) ex = (t == 0) ? 0 : cnt[t - 1];
    __syncthreads();
    if (t < nb) {
        mydeg = cnt[t] - ex;
        deg[nb0 + t] = mydeg;
        row_start[nb0 + t] = b * CAP + ex;
        cur[t] = ex;
        int dc = mydeg < 64 ? mydeg : 63;
        atomicAdd(&hcnt[dc], 1);
    }
    __syncthreads();
    for (int j = t; j < ec; j += 256) {
        unsigned w = stg[j];
        int r = atomicAdd(&cur[(w >> 16) & 127], 1);
        srt[r] = (unsigned short)(w & 0xFFFFu);
    }
    for (int off = 1; off < 64; off <<= 1) {
        int a = 0;
        if (t < 64 && t >= off) a = hcnt[t - off];
        __syncthreads();
        if (t < 64) hcnt[t] += a;
        __syncthreads();
    }
    int hex = 0;
    if (t < 64) hex = (t == 0) ? 0 : hcnt[t - 1];
    __syncthreads();
    if (t < 64) hcnt[t] = hex;   // hcnt becomes cursor
    __syncthreads();
    if (t < nb) {
        int dc = mydeg < 64 ? mydeg : 63;
        int rank = atomicAdd(&hcnt[dc], 1);
        perm[nb0 + rank] = nb0 + t;
    }
    __syncthreads();
    for (int j = t; j < ec; j += 256)
        col16[(size_t)b * CAP + j] = srt[j];
}

// ---------------------------------------------------------------------------
// Gather phase (device fn): 8 waves x 8 nodes -> 64-row LDS t-tile (bf16).
// Group striping: wave wv of block blk handles perm-group gid = wv*XBLK+blk.
__device__ __forceinline__ void gather_to_lds(const unsigned short* __restrict__ feat,
                                              const int* __restrict__ row_start,
                                              const int* __restrict__ deg,
                                              const unsigned short* __restrict__ col16,
                                              const int* __restrict__ perm,
                                              const float* __restrict__ bias,
                                              unsigned short* __restrict__ t_lds,
                                              int* __restrict__ nodetab,
                                              int wv, int lane, int blk) {
    const int g = lane >> 3, cl = lane & 7;
    const int lslot = wv * 8 + g;
    const int gid = wv * XBLK + blk;
    const bool active = gid < NGRP;
    const int node = active ? perm[gid * 8 + g] : -1;
    if (cl == 0) nodetab[lslot] = node;

    const unsigned int* f32p = (const unsigned int*)feat;
    int d = active ? deg[node] : 0;
    const int rs = active ? row_start[node] : 0;
    int dmax = d;
    dmax = max(dmax, __shfl_xor(dmax, 8, 64));
    dmax = max(dmax, __shfl_xor(dmax, 16, 64));
    dmax = max(dmax, __shfl_xor(dmax, 32, 64));

    float a0 = 0.f, a1 = 0.f, a2 = 0.f, a3 = 0.f;
    float a4 = 0.f, a5 = 0.f, a6 = 0.f, a7 = 0.f;
    if (active) {
        const float4* b4 = (const float4*)bias;
        float4 bb0 = b4[cl * 2], bb1 = b4[cl * 2 + 1];
        uint4 sv = *(const uint4*)(f32p + (size_t)node * 32 + cl * 4);
        a0 = b2f_lo(sv.x) + bb0.x; a1 = b2f_hi(sv.x) + bb0.y;
        a2 = b2f_lo(sv.y) + bb0.z; a3 = b2f_hi(sv.y) + bb0.w;
        a4 = b2f_lo(sv.z) + bb1.x; a5 = b2f_hi(sv.z) + bb1.y;
        a6 = b2f_lo(sv.w) + bb1.z; a7 = b2f_hi(sv.w) + bb1.w;
    }
    for (int rb = 0; rb < dmax; rb += 8) {
        int stage = (rb + cl < d) ? (int)col16[(size_t)rs + rb + cl] : 0;
#pragma unroll
        for (int e = 0; e < 8; ++e) {
            int s = __shfl(stage, g * 8 + e, 64);
            if (rb + e < d) {
                uint4 v = *(const uint4*)(f32p + (size_t)s * 32 + cl * 4);
                a0 += b2f_lo(v.x); a1 += b2f_hi(v.x);
                a2 += b2f_lo(v.y); a3 += b2f_hi(v.y);
                a4 += b2f_lo(v.z); a5 += b2f_hi(v.z);
                a6 += b2f_lo(v.w); a7 += b2f_hi(v.w);
            }
        }
    }
    uint4 o;
    o.x = pk2(a0, a1); o.y = pk2(a2, a3);
    o.z = pk2(a4, a5); o.w = pk2(a6, a7);
    *(uint4*)(t_lds + (size_t)lslot * LDP + cl * 8) = o;
}

// ---------------------------------------------------------------------------
// layer1: gather(xw,+b1a,relu)->LDS | barrier | waves 0-3:
//   h = relu(t@w1bT+b1b) -> LDS ; p[node] = h@w2aT (bf16)
__global__ __launch_bounds__(512) void layer1(const unsigned short* __restrict__ xw,
                                              const int* __restrict__ row_start,
                                              const int* __restrict__ deg,
                                              const unsigned short* __restrict__ col16,
                                              const int* __restrict__ perm,
                                              const float* __restrict__ b1a,
                                              const unsigned short* __restrict__ w1bT,
                                              const float* __restrict__ b1b,
                                              const unsigned short* __restrict__ w2aT,
                                              unsigned short* __restrict__ p) {
    __shared__ __align__(16) unsigned short t_lds[64 * LDP];
    __shared__ __align__(16) unsigned short h_lds[4][16 * LDP];
    __shared__ int nodetab[64];
    const int wv = threadIdx.x >> 6, lane = threadIdx.x & 63;

    gather_to_lds(xw, row_start, deg, col16, perm, b1a, t_lds, nodetab,
                  wv, lane, blockIdx.x);
    __syncthreads();
    if (wv >= 4) return;

    const int r = lane & 15, hk = lane >> 4;
    const unsigned short* tw = t_lds + wv * 16 * LDP;
    unsigned short* hw = h_lds[wv];

    f32x4 acc[4];
#pragma unroll
    for (int ct = 0; ct < 4; ++ct) {
        float bbv = b1b[16 * ct + r];
        acc[ct][0] = bbv; acc[ct][1] = bbv; acc[ct][2] = bbv; acc[ct][3] = bbv;
    }
#pragma unroll
    for (int s = 0; s < 2; ++s) {
        short8 a = *(const short8*)(tw + r * LDP + 32 * s + 8 * hk);
#pragma unroll
        for (int ct = 0; ct < 4; ++ct) {
            short8 b = *(const short8*)(w1bT + (16 * ct + r) * 64 + 32 * s + 8 * hk);
            acc[ct] = __builtin_amdgcn_mfma_f32_16x16x32_bf16(a, b, acc[ct], 0, 0, 0);
        }
    }
#pragma unroll
    for (int ct = 0; ct < 4; ++ct)
#pragma unroll
        for (int reg = 0; reg < 4; ++reg)
            hw[(4 * hk + reg) * LDP + 16 * ct + r] = f2b(fmaxf(acc[ct][reg], 0.f));

    f32x4 acc2[4] = {};
#pragma unroll
    for (int s = 0; s < 2; ++s) {
        short8 a = *(const short8*)(hw + r * LDP + 32 * s + 8 * hk);
#pragma unroll
        for (int ct = 0; ct < 4; ++ct) {
            short8 b = *(const short8*)(w2aT + (16 * ct + r) * 64 + 32 * s + 8 * hk);
            acc2[ct] = __builtin_amdgcn_mfma_f32_16x16x32_bf16(a, b, acc2[ct], 0, 0, 0);
        }
    }
#pragma unroll
    for (int reg = 0; reg < 4; ++reg) {
        int node = nodetab[wv * 16 + 4 * hk + reg];
        if (node >= 0) {
#pragma unroll
            for (int ct = 0; ct < 4; ++ct)
                p[(size_t)node * HID + 16 * ct + r] = f2b(acc2[ct][reg]);
        }
    }
}

// ---------------------------------------------------------------------------
// layer2: gather(p,+b2a,relu)->LDS | barrier | waves 0-3:
//   z = t@w2bT + b2b ; in-register log_softmax ; out[node] f32
__global__ __launch_bounds__(512) void layer2(const unsigned short* __restrict__ pin,
                                              const int* __restrict__ row_start,
                                              const int* __restrict__ deg,
                                              const unsigned short* __restrict__ col16,
                                              const int* __restrict__ perm,
                                              const float* __restrict__ b2a,
                                              const unsigned short* __restrict__ w2bT,
                                              const float* __restrict__ b2b,
                                              float* __restrict__ out) {
    __shared__ __align__(16) unsigned short t_lds[64 * LDP];
    __shared__ int nodetab[64];
    const int wv = threadIdx.x >> 6, lane = threadIdx.x & 63;

    gather_to_lds(pin, row_start, deg, col16, perm, b2a, t_lds, nodetab,
                  wv, lane, blockIdx.x);
    __syncthreads();
    if (wv >= 4) return;

    const int r = lane & 15, hk = lane >> 4;
    const unsigned short* tw = t_lds + wv * 16 * LDP;

    f32x4 acc[4];
#pragma unroll
    for (int ct = 0; ct < 4; ++ct) {
        float bbv = b2b[16 * ct + r];
        acc[ct][0] = bbv; acc[ct][1] = bbv; acc[ct][2] = bbv; acc[ct][3] = bbv;
    }
#pragma unroll
    for (int s = 0; s < 2; ++s) {
        short8 a = *(const short8*)(tw + r * LDP + 32 * s + 8 * hk);
#pragma unroll
        for (int ct = 0; ct < 4; ++ct) {
            short8 b = *(const short8*)(w2bT + (16 * ct + r) * 64 + 32 * s + 8 * hk);
            acc[ct] = __builtin_amdgcn_mfma_f32_16x16x32_bf16(a, b, acc[ct], 0, 0, 0);
        }
    }
#pragma unroll
    for (int reg = 0; reg < 4; ++reg) {
        float m = fmaxf(fmaxf(acc[0][reg], acc[1][reg]),
                        fmaxf(acc[2][reg], acc[3][reg]));
        for (int off = 1; off < 16; off <<= 1)
            m = fmaxf(m, __shfl_xor(m, off, 64));
        float s = expf(acc[0][reg] - m) + expf(acc[1][reg] - m) +
                  expf(acc[2][reg] - m) + expf(acc[3][reg] - m);
        for (int off = 1; off < 16; off <<= 1)
            s += __shfl_xor(s, off, 64);
        float ls = m + logf(s);
        int node = nodetab[wv * 16 + 4 * hk + reg];
        if (node >= 0) {
            float* op = out + (size_t)node * HID;
            op[r]      = acc[0][reg] - ls;
            op[16 + r] = acc[1][reg] - ls;
            op[32 + r] = acc[2][reg] - ls;
            op[48 + r] = acc[3][reg] - ls;
        }
    }
}

// ---------------------------------------------------------------------------
extern "C" void kernel_launch(void* const* d_in, const int* in_sizes, int n_in,
                              void* d_out, int out_size, void* d_ws, size_t ws_size,
                              hipStream_t stream) {
    const float* x   = (const float*)d_in[0];
    const int*   e32 = (const int*)d_in[1];
    const float* w1a = (const float*)d_in[2];
    const float* b1a = (const float*)d_in[3];
    const float* w1b = (const float*)d_in[4];
    const float* b1b = (const float*)d_in[5];
    const float* w2a = (const float*)d_in[6];
    const float* b2a = (const float*)d_in[7];
    const float* w2b = (const float*)d_in[8];
    const float* b2b = (const float*)d_in[9];
    float* out = (float*)d_out;

    // ws layout (32-bit words):
    // [gcur 512][col16 NBUK*CAP u16][row_start NN][deg NN][perm NN]
    // [xw NN*64 u16][p NN*64 u16 (binned u32 aliases it)]
    // [w1aT][w1bT][w2aT][w2bT]
    int* W = (int*)d_ws;
    int* gcur = W;                                            // 512 words
    unsigned short* col16 = (unsigned short*)(W + 512);       // NBUK*CAP u16
    int* row_start = W + 512 + (NBUK * CAP) / 2;              // even product
    int* deg       = row_start + NN;
    int* perm      = deg + NN;
    unsigned short* xw = (unsigned short*)(perm + NN);
    unsigned short* p  = xw + (size_t)NN * HID;
    unsigned int* binned = (unsigned int*)p;   // p unwritten until layer1
    unsigned short* w1aT = p + (size_t)NN * HID;
    unsigned short* w1bT = w1aT + 64 * 128;
    unsigned short* w2aT = w1bT + 64 * 64;
    unsigned short* w2bT = w2aT + 64 * 64;

    // 1. weights (bf16, transposed) + gcur zero
    wconv<<<81, 256, 0, stream>>>(w1a, w1b, w2a, w2b, w1aT, w1bT, w2aT, w2bT, gcur);

    // 2. bucket histogram sort co-dispatched with xw = x @ w1a
    binax<<<NTA + XBLK, 256, 0, stream>>>(e32, gcur, binned, x, w1aT, xw);

    // 3. per-bucket CSR + degree perm (short, sole dependency of layer1)
    binb<<<NBUK, 256, 0, stream>>>(gcur, binned, row_start, deg, col16, perm);

    // 4. layer 1 fused: gather+relu -> MLP(w1b,relu,w2a) -> p
    layer1<<<XBLK, 512, 0, stream>>>(xw, row_start, deg, col16, perm,
                                     b1a, w1bT, b1b, w2aT, p);

    // 5. layer 2 fused: gather+relu -> w2b + log_softmax -> out
    layer2<<<XBLK, 512, 0, stream>>>(p, row_start, deg, col16, perm,
                                     b2a, w2bT, b2b, out);
}

// Round 16
// 97.033 us; speedup vs baseline: 1.0356x; 1.0182x over previous
//
#include <hip/hip_runtime.h>
#include <stdint.h>

#define NN 50000
#define NE 800000
#define INC 128
#define HID 64
#define LDP 72     // padded LDS row stride (bf16 elems); 144B rows (16B-aligned)

#define NBUK 391   // ceil(NN/128) buckets; bucket = dst >> 7
#define CAP 2368   // edges/bucket capacity: mean 2048 + ~7 sigma
#define TILE 2048  // edges per binA tile
#define NTA 391    // ceil(NE/TILE); last tile has 1280 edges
#define XBLK 782   // ceil(NN/64) xform/layer blocks
#define NGRP 6250  // NN/8 perm groups
#define WCB 80     // wconv blocks (20480 weight elements / 256)

typedef __attribute__((ext_vector_type(8))) short short8;
typedef __attribute__((ext_vector_type(4))) float f32x4;

__device__ __forceinline__ unsigned short f2b(float f) {
    unsigned int u = __builtin_bit_cast(unsigned int, f);
    u += 0x7FFFu + ((u >> 16) & 1u);   // RNE (finite inputs)
    return (unsigned short)(u >> 16);
}
__device__ __forceinline__ float b2f_lo(unsigned int v) {
    return __builtin_bit_cast(float, v << 16);
}
__device__ __forceinline__ float b2f_hi(unsigned int v) {
    return __builtin_bit_cast(float, v & 0xFFFF0000u);
}
__device__ __forceinline__ unsigned int pk2(float lo, float hi) {
    return (unsigned int)f2b(fmaxf(lo, 0.f)) |
           ((unsigned int)f2b(fmaxf(hi, 0.f)) << 16);
}

// ---------------------------------------------------------------------------
// Edge-dtype detection: int64 LE with values <50000 => odd 32-bit words all 0.
__device__ __forceinline__ bool is_i32(const int* __restrict__ e32) {
    return (e32[1] | e32[3] | e32[5] | e32[7]) != 0;
}
__device__ __forceinline__ int load_src(const int* e32, bool i32, int e) {
    return i32 ? e32[e] : e32[2 * e];
}
__device__ __forceinline__ int load_dst(const int* e32, bool i32, int e) {
    return i32 ? e32[NE + e] : e32[2 * (NE + e)];
}

// ---------------------------------------------------------------------------
// Dispatch 1: blocks [0,NTA) = binA' (atomic-free deterministic binning);
// blocks [NTA, NTA+WCB) = wconv (weight transpose + bf16). Independent work.
// binA' tile t: LDS-sort 2048 edges by bucket, write them COALESCED to
// binned[t*TILE..], and write per-bucket exclusive offsets to
// offmat[b][t] (row NBUK = tile edge count sentinel).
__global__ __launch_bounds__(256) void binawc(const int* __restrict__ e32,
                                              unsigned int* __restrict__ binned,
                                              int* __restrict__ offmat,
                                              const float* __restrict__ w1a,
                                              const float* __restrict__ w1b,
                                              const float* __restrict__ w2a,
                                              const float* __restrict__ w2b,
                                              unsigned short* __restrict__ w1aT,
                                              unsigned short* __restrict__ w1bT,
                                              unsigned short* __restrict__ w2aT,
                                              unsigned short* __restrict__ w2bT) {
    __shared__ unsigned int stage[TILE];
    __shared__ unsigned int sorted[TILE];
    __shared__ int cnt[512];
    __shared__ int off0[512];

    if (blockIdx.x >= NTA) {
        // ---- wconv part ----
        int i = (blockIdx.x - NTA) * 256 + threadIdx.x;
        if (i < 8192) {
            int n = i >> 7, k = i & 127;
            w1aT[n * 128 + k] = f2b(w1a[k * 64 + n]);
        } else if (i < 12288) {
            int j = i - 8192, n = j >> 6, k = j & 63;
            w1bT[n * 64 + k] = f2b(w1b[k * 64 + n]);
        } else if (i < 16384) {
            int j = i - 12288, n = j >> 6, k = j & 63;
            w2aT[n * 64 + k] = f2b(w2a[k * 64 + n]);
        } else if (i < 20480) {
            int j = i - 16384, n = j >> 6, k = j & 63;
            w2bT[n * 64 + k] = f2b(w2b[k * 64 + n]);
        }
        return;
    }

    // ---- binA' part ----
    const int t = threadIdx.x;
    const int tile = blockIdx.x;
    const bool i32m = is_i32(e32);
    cnt[t] = 0; cnt[t + 256] = 0;
    __syncthreads();

    const int tb = tile * TILE;
    int nval = NE - tb; if (nval > TILE) nval = TILE;

    for (int k = 0; k < TILE; k += 256) {
        int j = k + t;
        if (j < nval) {
            int e = tb + j;
            int src = load_src(e32, i32m, e);
            int dst = load_dst(e32, i32m, e);
            stage[j] = ((unsigned)dst << 16) | (unsigned)src;
            atomicAdd(&cnt[dst >> 7], 1);
        }
    }
    __syncthreads();

    // inclusive Hillis-Steele scan over 512 slots (2 per thread)
    for (int off = 1; off < 512; off <<= 1) {
        int a = (t >= off) ? cnt[t - off] : 0;
        int b2 = (t + 256 >= off) ? cnt[t + 256 - off] : 0;
        __syncthreads();
        cnt[t] += a; cnt[t + 256] += b2;
        __syncthreads();
    }
    int ex0 = (t == 0) ? 0 : cnt[t - 1];
    int ex1 = cnt[t + 255];
    __syncthreads();
    off0[t] = ex0; off0[t + 256] = ex1;
    cnt[t] = ex0; cnt[t + 256] = ex1;   // cnt becomes allocation cursor
    __syncthreads();

    // in-LDS counting sort (bucket-contiguous)
    for (int k = 0; k < TILE; k += 256) {
        int j = k + t;
        if (j < nval) {
            unsigned w = stage[j];
            int b = (int)(w >> 16) >> 7;
            int r = atomicAdd(&cnt[b], 1);
            sorted[r] = w;
        }
    }
    __syncthreads();

    // coalesced write-out at the tile's fixed slot + offset matrix
    for (int k = 0; k < TILE; k += 256) {
        int j = k + t;
        if (j < nval) binned[(size_t)tile * TILE + j] = sorted[j];
    }
    if (t < NBUK) offmat[t * NTA + tile] = off0[t];
    if (t + 256 < NBUK) offmat[(t + 256) * NTA + tile] = off0[t + 256];
    if (t == 0) offmat[NBUK * NTA + tile] = nval;   // sentinel row
}

// ---------------------------------------------------------------------------
// Dispatch 2: blocks [0,NBUK) = binB' (bucket CSR + degree perm, gathering
// its edges from NTA tile segments via offmat); blocks [NBUK,NBUK+XBLK) =
// xform (xw = x @ w1a via MFMA).
__global__ __launch_bounds__(256) void binbxf(const unsigned int* __restrict__ binned,
                                              const int* __restrict__ offmat,
                                              int* __restrict__ row_start,
                                              int* __restrict__ deg,
                                              unsigned short* __restrict__ col16,
                                              int* __restrict__ perm,
                                              const float* __restrict__ x,
                                              const unsigned short* __restrict__ w1aT,
                                              unsigned short* __restrict__ xw) {
    __shared__ unsigned int stg[CAP];
    __shared__ unsigned short srt[CAP];
    __shared__ int scanarr[512], carr[512], soff[NTA];
    __shared__ int cnt[128], cur[128];
    __shared__ int hcnt[64];

    if (blockIdx.x >= NBUK) {
        // ---- xform part ----
        const int w = threadIdx.x >> 6, lane = threadIdx.x & 63;
        const int r = lane & 15, hk = lane >> 4;
        const int nb = (blockIdx.x - NBUK) * 64 + w * 16;
        f32x4 acc[4] = {};
#pragma unroll
        for (int s = 0; s < 4; ++s) {  // K = 128 = 4 x 32
            int row = nb + r; if (row >= NN) row = NN - 1;
            const float* xp = x + (size_t)row * INC + 32 * s + 8 * hk;
            float4 u0 = *(const float4*)xp;
            float4 u1 = *(const float4*)(xp + 4);
            short8 a;
            a[0] = (short)f2b(u0.x); a[1] = (short)f2b(u0.y);
            a[2] = (short)f2b(u0.z); a[3] = (short)f2b(u0.w);
            a[4] = (short)f2b(u1.x); a[5] = (short)f2b(u1.y);
            a[6] = (short)f2b(u1.z); a[7] = (short)f2b(u1.w);
#pragma unroll
            for (int ct = 0; ct < 4; ++ct) {
                short8 b = *(const short8*)(w1aT + (16 * ct + r) * 128 + 32 * s + 8 * hk);
                acc[ct] = __builtin_amdgcn_mfma_f32_16x16x32_bf16(a, b, acc[ct], 0, 0, 0);
            }
        }
#pragma unroll
        for (int ct = 0; ct < 4; ++ct)
#pragma unroll
            for (int reg = 0; reg < 4; ++reg) {
                int node = nb + 4 * hk + reg;
                if (node < NN) xw[(size_t)node * HID + 16 * ct + r] = f2b(acc[ct][reg]);
            }
        return;
    }

    // ---- binB' part ----
    const int b = blockIdx.x, t = threadIdx.x;
    const int nb0 = b * 128;
    int nb = NN - nb0; if (nb > 128) nb = 128;

    // segment table: offsets + counts for this bucket in each tile
    {
        int j0 = t, j1 = t + 256;
        int c0 = 0, c1 = 0;
        if (j0 < NTA) {
            int s0 = offmat[b * NTA + j0];
            int s1 = offmat[(b + 1) * NTA + j0];
            soff[j0] = s0; c0 = s1 - s0;
        }
        if (j1 < NTA) {
            int s0 = offmat[b * NTA + j1];
            int s1 = offmat[(b + 1) * NTA + j1];
            soff[j1] = s0; c1 = s1 - s0;
        }
        scanarr[t] = c0; carr[t] = c0;
        scanarr[t + 256] = c1; carr[t + 256] = c1;
    }
    __syncthreads();
    // inclusive scan over 512 (2 per thread)
    for (int off = 1; off < 512; off <<= 1) {
        int a = (t >= off) ? scanarr[t - off] : 0;
        int b2 = (t + 256 >= off) ? scanarr[t + 256 - off] : 0;
        __syncthreads();
        scanarr[t] += a; scanarr[t + 256] += b2;
        __syncthreads();
    }
    int ec = scanarr[511]; if (ec > CAP) ec = CAP;

    // copy tile segments into stg (bucket edge list)
    for (int j = t; j < NTA; j += 256) {
        int c = carr[j];
        int dst = scanarr[j] - c;
        size_t src = (size_t)j * TILE + soff[j];
        for (int k = 0; k < c; ++k) {
            int d2 = dst + k;
            if (d2 < CAP) stg[d2] = binned[src + k];
        }
    }
    if (t < 128) cnt[t] = 0;
    if (t < 64) hcnt[t] = 0;
    __syncthreads();

    // per-node counts
    for (int j = t; j < ec; j += 256)
        atomicAdd(&cnt[(stg[j] >> 16) & 127], 1);
    __syncthreads();
    // inclusive scan over 128 node counts
    for (int off = 1; off < 128; off <<= 1) {
        int a = 0;
        if (t < 128 && t >= off) a = cnt[t - off];
        __syncthreads();
        if (t < 128) cnt[t] += a;
        __syncthreads();
    }
    int ex = 0, mydeg = 0;
    if (t < 128) ex = (t == 0) ? 0 : cnt[t - 1];
    __syncthreads();
    if (t < nb) {
        mydeg = cnt[t] - ex;
        deg[nb0 + t] = mydeg;
        row_start[nb0 + t] = b * CAP + ex;
        cur[t] = ex;
        int dc = mydeg < 64 ? mydeg : 63;
        atomicAdd(&hcnt[dc], 1);
    }
    __syncthreads();
    // sort edges by node
    for (int j = t; j < ec; j += 256) {
        unsigned w = stg[j];
        int r = atomicAdd(&cur[(w >> 16) & 127], 1);
        srt[r] = (unsigned short)(w & 0xFFFFu);
    }
    // degree-histogram scan (64 bins) -> degree-sorted perm
    for (int off = 1; off < 64; off <<= 1) {
        int a = 0;
        if (t < 64 && t >= off) a = hcnt[t - off];
        __syncthreads();
        if (t < 64) hcnt[t] += a;
        __syncthreads();
    }
    int hex = 0;
    if (t < 64) hex = (t == 0) ? 0 : hcnt[t - 1];
    __syncthreads();
    if (t < 64) hcnt[t] = hex;   // hcnt becomes cursor
    __syncthreads();
    if (t < nb) {
        int dc = mydeg < 64 ? mydeg : 63;
        int rank = atomicAdd(&hcnt[dc], 1);
        perm[nb0 + rank] = nb0 + t;
    }
    __syncthreads();
    for (int j = t; j < ec; j += 256)
        col16[(size_t)b * CAP + j] = srt[j];
}

// ---------------------------------------------------------------------------
// Gather phase (device fn): 8 waves x 8 nodes -> 64-row LDS t-tile (bf16).
// Group striping: wave wv of block blk handles perm-group gid = wv*XBLK+blk.
__device__ __forceinline__ void gather_to_lds(const unsigned short* __restrict__ feat,
                                              const int* __restrict__ row_start,
                                              const int* __restrict__ deg,
                                              const unsigned short* __restrict__ col16,
                                              const int* __restrict__ perm,
                                              const float* __restrict__ bias,
                                              unsigned short* __restrict__ t_lds,
                                              int* __restrict__ nodetab,
                                              int wv, int lane, int blk) {
    const int g = lane >> 3, cl = lane & 7;
    const int lslot = wv * 8 + g;
    const int gid = wv * XBLK + blk;
    const bool active = gid < NGRP;
    const int node = active ? perm[gid * 8 + g] : -1;
    if (cl == 0) nodetab[lslot] = node;

    const unsigned int* f32p = (const unsigned int*)feat;
    int d = active ? deg[node] : 0;
    const int rs = active ? row_start[node] : 0;
    int dmax = d;
    dmax = max(dmax, __shfl_xor(dmax, 8, 64));
    dmax = max(dmax, __shfl_xor(dmax, 16, 64));
    dmax = max(dmax, __shfl_xor(dmax, 32, 64));

    float a0 = 0.f, a1 = 0.f, a2 = 0.f, a3 = 0.f;
    float a4 = 0.f, a5 = 0.f, a6 = 0.f, a7 = 0.f;
    if (active) {
        const float4* b4 = (const float4*)bias;
        float4 bb0 = b4[cl * 2], bb1 = b4[cl * 2 + 1];
        uint4 sv = *(const uint4*)(f32p + (size_t)node * 32 + cl * 4);
        a0 = b2f_lo(sv.x) + bb0.x; a1 = b2f_hi(sv.x) + bb0.y;
        a2 = b2f_lo(sv.y) + bb0.z; a3 = b2f_hi(sv.y) + bb0.w;
        a4 = b2f_lo(sv.z) + bb1.x; a5 = b2f_hi(sv.z) + bb1.y;
        a6 = b2f_lo(sv.w) + bb1.z; a7 = b2f_hi(sv.w) + bb1.w;
    }
    for (int rb = 0; rb < dmax; rb += 8) {
        int stage = (rb + cl < d) ? (int)col16[(size_t)rs + rb + cl] : 0;
#pragma unroll
        for (int e = 0; e < 8; ++e) {
            int s = __shfl(stage, g * 8 + e, 64);
            if (rb + e < d) {
                uint4 v = *(const uint4*)(f32p + (size_t)s * 32 + cl * 4);
                a0 += b2f_lo(v.x); a1 += b2f_hi(v.x);
                a2 += b2f_lo(v.y); a3 += b2f_hi(v.y);
                a4 += b2f_lo(v.z); a5 += b2f_hi(v.z);
                a6 += b2f_lo(v.w); a7 += b2f_hi(v.w);
            }
        }
    }
    uint4 o;
    o.x = pk2(a0, a1); o.y = pk2(a2, a3);
    o.z = pk2(a4, a5); o.w = pk2(a6, a7);
    *(uint4*)(t_lds + (size_t)lslot * LDP + cl * 8) = o;
}

// ---------------------------------------------------------------------------
// layer1: gather(xw,+b1a,relu)->LDS | barrier | waves 0-3:
//   h = relu(t@w1bT+b1b) -> LDS ; p[node] = h@w2aT (bf16)
__global__ __launch_bounds__(512) void layer1(const unsigned short* __restrict__ xw,
                                              const int* __restrict__ row_start,
                                              const int* __restrict__ deg,
                                              const unsigned short* __restrict__ col16,
                                              const int* __restrict__ perm,
                                              const float* __restrict__ b1a,
                                              const unsigned short* __restrict__ w1bT,
                                              const float* __restrict__ b1b,
                                              const unsigned short* __restrict__ w2aT,
                                              unsigned short* __restrict__ p) {
    __shared__ __align__(16) unsigned short t_lds[64 * LDP];
    __shared__ __align__(16) unsigned short h_lds[4][16 * LDP];
    __shared__ int nodetab[64];
    const int wv = threadIdx.x >> 6, lane = threadIdx.x & 63;

    gather_to_lds(xw, row_start, deg, col16, perm, b1a, t_lds, nodetab,
                  wv, lane, blockIdx.x);
    __syncthreads();
    if (wv >= 4) return;

    const int r = lane & 15, hk = lane >> 4;
    const unsigned short* tw = t_lds + wv * 16 * LDP;
    unsigned short* hw = h_lds[wv];

    f32x4 acc[4];
#pragma unroll
    for (int ct = 0; ct < 4; ++ct) {
        float bbv = b1b[16 * ct + r];
        acc[ct][0] = bbv; acc[ct][1] = bbv; acc[ct][2] = bbv; acc[ct][3] = bbv;
    }
#pragma unroll
    for (int s = 0; s < 2; ++s) {
        short8 a = *(const short8*)(tw + r * LDP + 32 * s + 8 * hk);
#pragma unroll
        for (int ct = 0; ct < 4; ++ct) {
            short8 b = *(const short8*)(w1bT + (16 * ct + r) * 64 + 32 * s + 8 * hk);
            acc[ct] = __builtin_amdgcn_mfma_f32_16x16x32_bf16(a, b, acc[ct], 0, 0, 0);
        }
    }
#pragma unroll
    for (int ct = 0; ct < 4; ++ct)
#pragma unroll
        for (int reg = 0; reg < 4; ++reg)
            hw[(4 * hk + reg) * LDP + 16 * ct + r] = f2b(fmaxf(acc[ct][reg], 0.f));

    f32x4 acc2[4] = {};
#pragma unroll
    for (int s = 0; s < 2; ++s) {
        short8 a = *(const short8*)(hw + r * LDP + 32 * s + 8 * hk);
#pragma unroll
        for (int ct = 0; ct < 4; ++ct) {
            short8 b = *(const short8*)(w2aT + (16 * ct + r) * 64 + 32 * s + 8 * hk);
            acc2[ct] = __builtin_amdgcn_mfma_f32_16x16x32_bf16(a, b, acc2[ct], 0, 0, 0);
        }
    }
#pragma unroll
    for (int reg = 0; reg < 4; ++reg) {
        int node = nodetab[wv * 16 + 4 * hk + reg];
        if (node >= 0) {
#pragma unroll
            for (int ct = 0; ct < 4; ++ct)
                p[(size_t)node * HID + 16 * ct + r] = f2b(acc2[ct][reg]);
        }
    }
}

// ---------------------------------------------------------------------------
// layer2: gather(p,+b2a,relu)->LDS | barrier | waves 0-3:
//   z = t@w2bT + b2b ; in-register log_softmax ; out[node] f32
__global__ __launch_bounds__(512) void layer2(const unsigned short* __restrict__ pin,
                                              const int* __restrict__ row_start,
                                              const int* __restrict__ deg,
                                              const unsigned short* __restrict__ col16,
                                              const int* __restrict__ perm,
                                              const float* __restrict__ b2a,
                                              const unsigned short* __restrict__ w2bT,
                                              const float* __restrict__ b2b,
                                              float* __restrict__ out) {
    __shared__ __align__(16) unsigned short t_lds[64 * LDP];
    __shared__ int nodetab[64];
    const int wv = threadIdx.x >> 6, lane = threadIdx.x & 63;

    gather_to_lds(pin, row_start, deg, col16, perm, b2a, t_lds, nodetab,
                  wv, lane, blockIdx.x);
    __syncthreads();
    if (wv >= 4) return;

    const int r = lane & 15, hk = lane >> 4;
    const unsigned short* tw = t_lds + wv * 16 * LDP;

    f32x4 acc[4];
#pragma unroll
    for (int ct = 0; ct < 4; ++ct) {
        float bbv = b2b[16 * ct + r];
        acc[ct][0] = bbv; acc[ct][1] = bbv; acc[ct][2] = bbv; acc[ct][3] = bbv;
    }
#pragma unroll
    for (int s = 0; s < 2; ++s) {
        short8 a = *(const short8*)(tw + r * LDP + 32 * s + 8 * hk);
#pragma unroll
        for (int ct = 0; ct < 4; ++ct) {
            short8 b = *(const short8*)(w2bT + (16 * ct + r) * 64 + 32 * s + 8 * hk);
            acc[ct] = __builtin_amdgcn_mfma_f32_16x16x32_bf16(a, b, acc[ct], 0, 0, 0);
        }
    }
#pragma unroll
    for (int reg = 0; reg < 4; ++reg) {
        float m = fmaxf(fmaxf(acc[0][reg], acc[1][reg]),
                        fmaxf(acc[2][reg], acc[3][reg]));
        for (int off = 1; off < 16; off <<= 1)
            m = fmaxf(m, __shfl_xor(m, off, 64));
        float s = expf(acc[0][reg] - m) + expf(acc[1][reg] - m) +
                  expf(acc[2][reg] - m) + expf(acc[3][reg] - m);
        for (int off = 1; off < 16; off <<= 1)
            s += __shfl_xor(s, off, 64);
        float ls = m + logf(s);
        int node = nodetab[wv * 16 + 4 * hk + reg];
        if (node >= 0) {
            float* op = out + (size_t)node * HID;
            op[r]      = acc[0][reg] - ls;
            op[16 + r] = acc[1][reg] - ls;
            op[32 + r] = acc[2][reg] - ls;
            op[48 + r] = acc[3][reg] - ls;
        }
    }
}

// ---------------------------------------------------------------------------
extern "C" void kernel_launch(void* const* d_in, const int* in_sizes, int n_in,
                              void* d_out, int out_size, void* d_ws, size_t ws_size,
                              hipStream_t stream) {
    const float* x   = (const float*)d_in[0];
    const int*   e32 = (const int*)d_in[1];
    const float* w1a = (const float*)d_in[2];
    const float* b1a = (const float*)d_in[3];
    const float* w1b = (const float*)d_in[4];
    const float* b1b = (const float*)d_in[5];
    const float* w2a = (const float*)d_in[6];
    const float* b2a = (const float*)d_in[7];
    const float* w2b = (const float*)d_in[8];
    const float* b2b = (const float*)d_in[9];
    float* out = (float*)d_out;

    // ws layout (32-bit words):
    // [col16 NBUK*CAP u16][row_start NN][deg NN][perm NN]
    // [offmat (NBUK+1)*NTA][xw NN*64 u16][p NN*64 u16 (binned u32 aliases it)]
    // [w1aT][w1bT][w2aT][w2bT]
    int* W = (int*)d_ws;
    unsigned short* col16 = (unsigned short*)W;               // NBUK*CAP u16
    int* row_start = W + (NBUK * CAP) / 2;                    // even product
    int* deg       = row_start + NN;
    int* perm      = deg + NN;
    int* offmat    = perm + NN;                               // 392*391 words
    unsigned short* xw = (unsigned short*)(offmat + (NBUK + 1) * NTA);
    unsigned short* p  = xw + (size_t)NN * HID;
    unsigned int* binned = (unsigned int*)p;   // 800K u32, p unwritten till layer1
    unsigned short* w1aT = p + (size_t)NN * HID;
    unsigned short* w1bT = w1aT + 64 * 128;
    unsigned short* w2aT = w1bT + 64 * 64;
    unsigned short* w2bT = w2aT + 64 * 64;

    // 1. atomic-free tile binning (+offmat)  ||  weight transpose->bf16
    binawc<<<NTA + WCB, 256, 0, stream>>>(e32, binned, offmat,
                                          w1a, w1b, w2a, w2b,
                                          w1aT, w1bT, w2aT, w2bT);

    // 2. per-bucket CSR + degree perm  ||  xw = x @ w1a (MFMA)
    binbxf<<<NBUK + XBLK, 256, 0, stream>>>(binned, offmat, row_start, deg,
                                            col16, perm, x, w1aT, xw);

    // 3. layer 1 fused: gather+relu -> MLP(w1b,relu,w2a) -> p
    layer1<<<XBLK, 512, 0, stream>>>(xw, row_start, deg, col16, perm,
                                     b1a, w1bT, b1b, w2aT, p);

    // 4. layer 2 fused: gather+relu -> w2b + log_softmax -> out
    layer2<<<XBLK, 512, 0, stream>>>(p, row_start, deg, col16, perm,
                                     b2a, w2bT, b2b, out);
}